// Round 1
// 205.336 us; speedup vs baseline: 1.1351x; 1.1351x over previous
//
#include <hip/hip_runtime.h>

#define DM 1024
#define NHEADS 16
#define DHEAD 64
#define BB 2
#define SS 2048
#define BH (BB*NHEADS)

typedef __attribute__((ext_vector_type(8))) short short8;
typedef __attribute__((ext_vector_type(4))) float float4v;
typedef unsigned short ushort_t;

#define LN1E4_D32 0.28782313662425572f   // ln(10000)/32

static __device__ __forceinline__ unsigned short f2bf(float f) {
    union { float f; unsigned u; } v; v.f = f;
    unsigned r = v.u + 0x7fffu + ((v.u >> 16) & 1u);
    return (unsigned short)(r >> 16);
}
static __device__ __forceinline__ float bf2f(unsigned short u) {
    union { float f; unsigned u; } v; v.u = ((unsigned)u) << 16;
    return v.f;
}

// load 8 f32, round to bf16, store one 16B LDS word (gemm3 staging)
static __device__ __forceinline__ void cvt8(const float* __restrict__ src, ushort_t* dst) {
    float4 a0 = *reinterpret_cast<const float4*>(src);
    float4 a1 = *reinterpret_cast<const float4*>(src + 4);
    short8 v;
    v[0] = (short)f2bf(a0.x); v[1] = (short)f2bf(a0.y);
    v[2] = (short)f2bf(a0.z); v[3] = (short)f2bf(a0.w);
    v[4] = (short)f2bf(a1.x); v[5] = (short)f2bf(a1.y);
    v[6] = (short)f2bf(a1.z); v[7] = (short)f2bf(a1.w);
    *reinterpret_cast<short8*>(dst) = v;
}

// async global->LDS 16B copy: lds dest is wave-uniform base + lane*16
static __device__ __forceinline__ void gload16(const ushort_t* g, ushort_t* l) {
    __builtin_amdgcn_global_load_lds(
        (const __attribute__((address_space(1))) void*)g,
        (__attribute__((address_space(3))) void*)l, 16, 0, 0);
}

// ---------------- RoPE on K = heads(y): f32 roped K (output 1) + bf16 swizzled tiles (ws) ----
// bf16 tile layout: [bh][kt=s>>6] 8KB tile; element (key=s&63, dh) at
//   key*64 + (((dh>>3) ^ (key&7))<<3) + (dh&7)   (ushort units)
// The XOR swizzle makes the attn QK ds_read_b128 pattern bank-conflict-free (G4).
__global__ __launch_bounds__(256) void rope_k_kernel(const float* __restrict__ y,
        float* __restrict__ kout, ushort_t* __restrict__ khb) {
    int t = blockIdx.x * blockDim.x + threadIdx.x;   // (bh, s, i8)
    int i8 = t & 3;
    int s  = (t >> 2) & (SS - 1);
    int bh = t >> 13;
    int h = bh & (NHEADS - 1), b = bh >> 4;

    const float* yp = y + ((size_t)(b * SS + s)) * DM + h * DHEAD + i8 * 8;
    float4 a0 = *reinterpret_cast<const float4*>(yp);
    float4 a1 = *reinterpret_cast<const float4*>(yp + 4);
    float4 b0 = *reinterpret_cast<const float4*>(yp + 32);
    float4 b1 = *reinterpret_cast<const float4*>(yp + 36);
    float u0[8] = {a0.x, a0.y, a0.z, a0.w, a1.x, a1.y, a1.z, a1.w};
    float u1[8] = {b0.x, b0.y, b0.z, b0.w, b1.x, b1.y, b1.z, b1.w};
    float lo[8], hi[8];
#pragma unroll
    for (int j = 0; j < 8; j++) {
        int i = i8 * 8 + j;
        float freq = __expf(-(float)i * LN1E4_D32);
        float th = (float)s * freq;
        float cv = cosf(th), sv = sinf(th);   // precise: feeds f32 output directly
        lo[j] = u0[j] * cv - u1[j] * sv;
        hi[j] = u1[j] * cv + u0[j] * sv;
    }
    float* op = kout + ((size_t)bh * SS + s) * DHEAD + i8 * 8;
    *reinterpret_cast<float4*>(op)      = (float4){lo[0], lo[1], lo[2], lo[3]};
    *reinterpret_cast<float4*>(op + 4)  = (float4){lo[4], lo[5], lo[6], lo[7]};
    *reinterpret_cast<float4*>(op + 32) = (float4){hi[0], hi[1], hi[2], hi[3]};
    *reinterpret_cast<float4*>(op + 36) = (float4){hi[4], hi[5], hi[6], hi[7]};

    // bf16 swizzled tiles: chunk d4=i8 (dh<32) and d4=i8+4 (dh>=32)
    ushort_t* kb = khb + ((size_t)bh * 32 + (s >> 6)) * 4096 + (s & 63) * 64;
    short8 vlo, vhi;
#pragma unroll
    for (int j = 0; j < 8; j++) { vlo[j] = (short)f2bf(lo[j]); vhi[j] = (short)f2bf(hi[j]); }
    *reinterpret_cast<short8*>(kb + ((i8 ^ (s & 7)) << 3))       = vlo;
    *reinterpret_cast<short8*>(kb + (((i8 + 4) ^ (s & 7)) << 3)) = vhi;
}

// ---------------- 3 projection GEMMs (f32 in, bf16 MFMA) ----------------
// z=0: Q = rope(x*wq^T) -> heads-layout bf16 ; z=1: V = y*wv^T -> PRE-TRANSPOSED swizzled
// V^T tiles [bh][kt][dh][key] ; z=2: V1 = x*wo^T -> heads-layout bf16
__global__ __launch_bounds__(256, 2) void gemm3_kernel(
        const float* __restrict__ x, const float* __restrict__ y,
        const float* __restrict__ wq, const float* __restrict__ wv,
        const float* __restrict__ wo,
        ushort_t* __restrict__ qh, ushort_t* __restrict__ vt, ushort_t* __restrict__ v1h) {
    __shared__ __align__(16) char smem[34816];
    ushort_t (*As)[40] = (ushort_t(*)[40])smem;
    ushort_t (*Bs)[40] = (ushort_t(*)[40])(smem + 10240);
    ushort_t (*Ct)[136] = (ushort_t(*)[136])smem;

    int bid = blockIdx.x;
    int xcd = bid & 7;
    int s_  = bid >> 3;
    int zo  = s_ >> 5;
    int z   = (zo == 0) ? 0 : (zo == 1 ? 2 : 1);
    int t_  = s_ & 31;
    int n0  = (t_ >> 2) * 128;
    int m0  = (xcd * 4 + (t_ & 3)) * 128;

    const float* A = (z == 1) ? y : x;
    const float* W = (z == 0) ? wq : (z == 1 ? wv : wo);
    ushort_t* O = (z == 0) ? qh : (z == 1 ? vt : v1h);

    int tid = threadIdx.x;
    int wave = tid >> 6, lane = tid & 63, quad = lane >> 4, l15 = lane & 15;
    int wr = (wave >> 1) * 64, wc = (wave & 1) * 64;
    float4v acc[4][4];
#pragma unroll
    for (int a = 0; a < 4; a++)
#pragma unroll
        for (int b = 0; b < 4; b++)
            acc[a][b] = (float4v){0.f, 0.f, 0.f, 0.f};

    for (int k0 = 0; k0 < DM; k0 += 32) {
#pragma unroll
        for (int c = tid; c < 512; c += 256) {
            int row = c >> 2, cc = (c & 3) * 8;
            cvt8(&A[(m0 + row) * DM + k0 + cc], &As[row][cc]);
            cvt8(&W[(n0 + row) * DM + k0 + cc], &Bs[row][cc]);
        }
        __syncthreads();
        short8 af[4], bfr[4];
#pragma unroll
        for (int mi = 0; mi < 4; mi++)
            af[mi] = *reinterpret_cast<const short8*>(&As[wr + mi * 16 + l15][quad * 8]);
#pragma unroll
        for (int ni = 0; ni < 4; ni++)
            bfr[ni] = *reinterpret_cast<const short8*>(&Bs[wc + ni * 16 + l15][quad * 8]);
#pragma unroll
        for (int mi = 0; mi < 4; mi++)
#pragma unroll
            for (int ni = 0; ni < 4; ni++)
                acc[mi][ni] = __builtin_amdgcn_mfma_f32_16x16x32_bf16(af[mi], bfr[ni], acc[mi][ni], 0, 0, 0);
        __syncthreads();
    }

    if (z == 0) {
#pragma unroll
        for (int mi = 0; mi < 4; mi++)
#pragma unroll
            for (int r = 0; r < 4; r++) {
                int m = m0 + wr + mi * 16 + quad * 4 + r;
                float pos = (float)(m & (SS - 1));
#pragma unroll
                for (int ni = 0; ni < 2; ni++) {
                    int d = ni * 16 + l15;
                    float f = __expf(-(float)d * LN1E4_D32);
                    float th = pos * f;
                    float cv, sv;
                    __sincosf(th, &sv, &cv);
                    float u0 = acc[mi][ni][r], u1 = acc[mi][ni + 2][r];
                    acc[mi][ni][r]     = u0 * cv - u1 * sv;
                    acc[mi][ni + 2][r] = u1 * cv + u0 * sv;
                }
            }
    }

    __syncthreads();
#pragma unroll
    for (int mi = 0; mi < 4; mi++)
#pragma unroll
        for (int ni = 0; ni < 4; ni++) {
            int col = wc + ni * 16 + l15;
#pragma unroll
            for (int r = 0; r < 4; r++)
                Ct[wr + mi * 16 + quad * 4 + r][col] = f2bf(acc[mi][ni][r]);
        }
    __syncthreads();
    int h0 = n0 >> 6;
    if (z == 1) {
        // V^T swizzled tile write: element (key, dh) -> dh*64 + (((key&63)>>3 ^ (dh&7))<<3) + (key&7)
        int b = m0 >> 11;
        int s0 = m0 & (SS - 1);
#pragma unroll
        for (int it = 0; it < 8; it++) {
            int c = it * 256 + tid;            // [0,2048) chunks of 16B
            int dh  = c & 63;                  // dh fastest: LDS column-gather stays conflict-free
            int k16 = (c >> 6) & 15;           // key octet within the 128-row C tile
            int hh  = c >> 10;
            short8 v;
#pragma unroll
            for (int e = 0; e < 8; e++)
                v[e] = (short)Ct[k16 * 8 + e][hh * 64 + dh];
            int kt = (s0 >> 6) + (k16 >> 3);
            size_t off = ((size_t)((b * NHEADS + h0 + hh) * 32 + kt)) * 4096
                       + dh * 64 + (((k16 & 7) ^ (dh & 7)) << 3);
            *reinterpret_cast<short8*>(&O[off]) = v;
        }
    } else {
#pragma unroll
        for (int it = 0; it < 8; it++) {
            int c = it * 256 + tid;
            int o = c >> 3, j = c & 7;
            int hh = o >> 7, mr = o & 127;
            int m = m0 + mr, b = m >> 11, si = m & (SS - 1);
            uint4 v = *reinterpret_cast<const uint4*>(&Ct[mr][hh * 64 + j * 8]);
            *reinterpret_cast<uint4*>(
                &O[((size_t)((b * NHEADS + h0 + hh) * SS + si)) * DHEAD + j * 8]) = v;
        }
    }
}

// ---------------- flash attention: pre-formatted bf16 K / V^T tiles, async double-buffered
// staging via global_load_lds, ONE barrier per tile (Ps/sdiag are per-wave -> no block sync).
__global__ __launch_bounds__(256, 2) void attn_kernel(
        const ushort_t* __restrict__ qh, const float* __restrict__ kf32,
        const ushort_t* __restrict__ khb, const ushort_t* __restrict__ vtb,
        const ushort_t* __restrict__ v1h, float* __restrict__ out) {
    __shared__ __align__(16) ushort_t Ks[2][4096];   // [key][dh] swizzled, 8KB per buffer
    __shared__ __align__(16) ushort_t Vt[2][4096];   // [dh][key] swizzled
    __shared__ ushort_t Ps[4][16][68];               // per-wave P round-trip [q][key]
    __shared__ float sdiag[4][16];

    int bid = blockIdx.x;
    int bh = (bid & 7) * 4 + ((bid >> 3) & 3);
    int qb = 31 - (bid >> 5);
    int q0 = qb * 64;

    int tid = threadIdx.x, wave = tid >> 6, lane = tid & 63, quad = lane >> 4, l15 = lane & 15;
    int q0w = q0 + wave * 16;
    const ushort_t* qp  = qh  + (size_t)bh * SS * DHEAD;
    const float*    kp  = kf32 + (size_t)bh * SS * DHEAD;
    const ushort_t* v1p = v1h + (size_t)bh * SS * DHEAD;
    const ushort_t* ktb = khb + (size_t)bh * 32 * 4096;
    const ushort_t* vtt = vtb + (size_t)bh * 32 * 4096;

    short8 qf[2];
    qf[0] = *reinterpret_cast<const short8*>(&qp[(q0w + l15) * DHEAD + quad * 8]);
    qf[1] = *reinterpret_cast<const short8*>(&qp[(q0w + l15) * DHEAD + 32 + quad * 8]);

    float4v Oa[4];
#pragma unroll
    for (int t = 0; t < 4; t++) Oa[t] = (float4v){0.f, 0.f, 0.f, 0.f};
    float lsum[4] = {0.f, 0.f, 0.f, 0.f};

    int gi0 = tid * 8, gi1 = (256 + tid) * 8;               // per-lane global chunk offsets
    int li0 = (tid & 192) * 8, li1 = (256 + (tid & 192)) * 8; // wave-uniform LDS bases

    int ntiles = qb + 1;
    // prologue: stage tile 0 into buffer 0
    gload16(ktb + gi0, &Ks[0][li0]); gload16(ktb + gi1, &Ks[0][li1]);
    gload16(vtt + gi0, &Vt[0][li0]); gload16(vtt + gi1, &Vt[0][li1]);
    int cur = 0;

    for (int kt = 0; kt < ntiles; kt++) {
        __syncthreads();   // drains vmcnt -> buf[cur] ready; prior reads of buf[cur^1] done
        if (kt + 1 < ntiles) {   // prefetch next tile; stays in flight across this compute
            const ushort_t* gk = ktb + (size_t)(kt + 1) * 4096;
            const ushort_t* gv = vtt + (size_t)(kt + 1) * 4096;
            int nb = cur ^ 1;
            gload16(gk + gi0, &Ks[nb][li0]); gload16(gk + gi1, &Ks[nb][li1]);
            gload16(gv + gi0, &Vt[nb][li0]); gload16(gv + gi1, &Vt[nb][li1]);
        }
        const ushort_t* Kc = Ks[cur];
        const ushort_t* Vc = Vt[cur];

        // S = Q K^T : four 16-key sub-tiles, swizzled conflict-free reads
        float4v sa[4];
#pragma unroll
        for (int t2 = 0; t2 < 4; t2++) sa[t2] = (float4v){0.f, 0.f, 0.f, 0.f};
#pragma unroll
        for (int t2 = 0; t2 < 4; t2++) {
            int key = t2 * 16 + l15;
            int ro = key * 64, sw = key & 7;
#pragma unroll
            for (int half = 0; half < 2; half++) {
                short8 kf = *reinterpret_cast<const short8*>(&Kc[ro + (((half * 4 + quad) ^ sw) << 3)]);
                sa[t2] = __builtin_amdgcn_mfma_f32_16x16x32_bf16(qf[half], kf, sa[t2], 0, 0, 0);
            }
        }

        // softmax, static max (safe: |s|<~2.5), per-lane partial l
        int kbase = kt * 64;
#pragma unroll
        for (int r = 0; r < 4; r++) {
            int query = q0w + quad * 4 + r;
#pragma unroll
            for (int t2 = 0; t2 < 4; t2++) {
                int key = kbase + t2 * 16 + l15;
                float p = (key <= query) ? __expf(sa[t2][r] * 0.125f) : 0.f;
                Ps[wave][quad * 4 + r][t2 * 16 + l15] = f2bf(p);
                lsum[r] += p;
            }
        }
        // Ps is per-wave: compiler-inserted lgkmcnt orders write->read, no block barrier
        short8 pf0 = *reinterpret_cast<const short8*>(&Ps[wave][l15][quad * 8]);
        short8 pf1 = *reinterpret_cast<const short8*>(&Ps[wave][l15][32 + quad * 8]);
#pragma unroll
        for (int t = 0; t < 4; t++) {
            int dh = t * 16 + l15;
            int ro = dh * 64, sw = dh & 7;
            short8 vf0 = *reinterpret_cast<const short8*>(&Vc[ro + ((quad ^ sw) << 3)]);
            short8 vf1 = *reinterpret_cast<const short8*>(&Vc[ro + (((4 + quad) ^ sw) << 3)]);
            Oa[t] = __builtin_amdgcn_mfma_f32_16x16x32_bf16(pf0, vf0, Oa[t], 0, 0, 0);
            Oa[t] = __builtin_amdgcn_mfma_f32_16x16x32_bf16(pf1, vf1, Oa[t], 0, 0, 0);
        }
        cur ^= 1;
    }

    // diagonal extra key: s_d = q[i] . rope(k_roped[i]) / 8, value v1[i]
    {
        int sk = q0w + l15;
        const float* krow = kp + (size_t)sk * DHEAD;
        short8 k1lo, k1hi;
#pragma unroll
        for (int j = 0; j < 8; j++) {
            int d = quad * 8 + j;
            float f = __expf(-(float)d * LN1E4_D32);
            float th = (float)sk * f;
            float cv, sv;
            __sincosf(th, &sv, &cv);
            float a = krow[d], b2 = krow[d + 32];
            k1lo[j] = (short)f2bf(a * cv - b2 * sv);
            k1hi[j] = (short)f2bf(b2 * cv + a * sv);
        }
        float4v sd4 = (float4v){0.f, 0.f, 0.f, 0.f};
        sd4 = __builtin_amdgcn_mfma_f32_16x16x32_bf16(qf[0], k1lo, sd4, 0, 0, 0);
        sd4 = __builtin_amdgcn_mfma_f32_16x16x32_bf16(qf[1], k1hi, sd4, 0, 0, 0);
#pragma unroll
        for (int r = 0; r < 4; r++)
            if (l15 == quad * 4 + r) sdiag[wave][l15] = sd4[r] * 0.125f;
        __syncthreads();

        int b = bh >> 4, h = bh & (NHEADS - 1);
#pragma unroll
        for (int r = 0; r < 4; r++) {
            float ls = lsum[r];
#pragma unroll
            for (int off = 1; off < 16; off <<= 1) ls += __shfl_xor(ls, off);
            float pd = __expf(sdiag[wave][quad * 4 + r]);
            int query = q0w + quad * 4 + r;
            float linv = 1.f / (ls + pd);
#pragma unroll
            for (int t = 0; t < 4; t++) {
                float v1v = bf2f(v1p[query * DHEAD + t * 16 + l15]);
                float o = (Oa[t][r] + pd * v1v) * linv;
                out[(b * SS + query) * DM + h * DHEAD + t * 16 + l15] = o;
            }
        }
    }
}

extern "C" void kernel_launch(void* const* d_in, const int* in_sizes, int n_in,
                              void* d_out, int out_size, void* d_ws, size_t ws_size,
                              hipStream_t stream) {
    const float* x  = (const float*)d_in[0];
    const float* y  = (const float*)d_in[1];
    const float* wq = (const float*)d_in[2];
    // d_in[3] = wk is unused by the reference
    const float* wv = (const float*)d_in[4];
    const float* wo = (const float*)d_in[5];
    float* outp  = (float*)d_out;                       // output 0: (2,2048,1024) f32
    float* k_out = outp + (size_t)BB * SS * DM;         // output 1: roped K (2,16,2048,64) f32

    char* ws = (char*)d_ws;
    ushort_t* vtb = (ushort_t*)(ws);                  // 8 MB  V^T swizzled tiles
    ushort_t* v1b = (ushort_t*)(ws + (8ull  << 20));  // 8 MB
    ushort_t* qhb = (ushort_t*)(ws + (16ull << 20));  // 8 MB
    ushort_t* khb = (ushort_t*)(ws + (24ull << 20));  // 8 MB  bf16 swizzled K tiles (32 MB total)

    rope_k_kernel<<<1024, 256, 0, stream>>>(y, k_out, khb);
    gemm3_kernel<<<768, 256, 0, stream>>>(x, y, wq, wv, wo, qhb, vtb, v1b);
    attn_kernel<<<1024, 256, 0, stream>>>(qhb, k_out, khb, vtb, v1b, outp);
}

// Round 2
// 184.649 us; speedup vs baseline: 1.2623x; 1.1120x over previous
//
#include <hip/hip_runtime.h>

#define DM 1024
#define NHEADS 16
#define DHEAD 64
#define BB 2
#define SS 2048
#define BH (BB*NHEADS)

typedef __attribute__((ext_vector_type(8))) short short8;
typedef __attribute__((ext_vector_type(4))) float float4v;
typedef unsigned short ushort_t;

#define LN1E4_D32 0.28782313662425572f   // ln(10000)/32

static __device__ __forceinline__ unsigned short f2bf(float f) {
    union { float f; unsigned u; } v; v.f = f;
    unsigned r = v.u + 0x7fffu + ((v.u >> 16) & 1u);
    return (unsigned short)(r >> 16);
}
static __device__ __forceinline__ float bf2f(unsigned short u) {
    union { float f; unsigned u; } v; v.u = ((unsigned)u) << 16;
    return v.f;
}

// async global->LDS 16B copy: lds dest is wave-uniform base + lane*16
static __device__ __forceinline__ void gload16(const ushort_t* g, ushort_t* l) {
    __builtin_amdgcn_global_load_lds(
        (const __attribute__((address_space(1))) void*)g,
        (__attribute__((address_space(3))) void*)l, 16, 0, 0);
}

// ---------------- prepass: f32 -> bf16 pre-swizzled 128x32 GEMM tiles ----------------
// Tile (rb,kb) is 8KB contiguous at (rb*32+kb)*4096 ushorts. Chunk c (0..511) = row*4+g
// holds elements (row, kk = ((g ^ ((row>>1)&3))<<3) + 0..7). This is the exact LDS image:
// global_load_lds copies it linearly, and the ds_read_b128 fragment reads
// (row*32 + ((quad ^ ((row>>1)&3))<<3)) are bank-conflict-free (each 8-lane group
// covers all 8 16B-granules of the 128B wrap exactly once).
__global__ __launch_bounds__(256) void cvt_tile_kernel(
        const float* __restrict__ x, const float* __restrict__ wq,
        const float* __restrict__ wv, const float* __restrict__ wo,
        ushort_t* __restrict__ xb, ushort_t* __restrict__ wqb,
        ushort_t* __restrict__ wvb, ushort_t* __restrict__ wob) {
    int C = blockIdx.x * 256 + threadIdx.x;   // 56 row-tiles * 32 kb * 512 chunks = 917504
    int c  = C & 511;
    int tl = C >> 9;                          // 0..1791
    int rb = tl >> 5, kb = tl & 31;
    const float* src; ushort_t* dst; int r0;
    if (rb < 32)      { src = x;  r0 = rb * 128;        dst = xb  + (size_t)tl * 4096; }
    else if (rb < 40) { src = wq; r0 = (rb - 32) * 128; dst = wqb + (size_t)(((rb - 32) * 32) + kb) * 4096; }
    else if (rb < 48) { src = wv; r0 = (rb - 40) * 128; dst = wvb + (size_t)(((rb - 40) * 32) + kb) * 4096; }
    else              { src = wo; r0 = (rb - 48) * 128; dst = wob + (size_t)(((rb - 48) * 32) + kb) * 4096; }
    int row = c >> 2, g = c & 3;
    int kk3 = g ^ ((row >> 1) & 3);
    const float* s = src + (size_t)(r0 + row) * DM + kb * 32 + kk3 * 8;
    float4 a0 = *reinterpret_cast<const float4*>(s);
    float4 a1 = *reinterpret_cast<const float4*>(s + 4);
    short8 v;
    v[0] = (short)f2bf(a0.x); v[1] = (short)f2bf(a0.y);
    v[2] = (short)f2bf(a0.z); v[3] = (short)f2bf(a0.w);
    v[4] = (short)f2bf(a1.x); v[5] = (short)f2bf(a1.y);
    v[6] = (short)f2bf(a1.z); v[7] = (short)f2bf(a1.w);
    *reinterpret_cast<short8*>(dst + c * 8) = v;
}

// ---------------- RoPE on K = heads(y): f32 roped K (output 1) + bf16 swizzled attn tiles
// + un-roped bf16 y GEMM tiles (A-operand of the V projection) ----------------
__global__ __launch_bounds__(256) void rope_k_kernel(const float* __restrict__ y,
        float* __restrict__ kout, ushort_t* __restrict__ khb, ushort_t* __restrict__ yb) {
    int t = blockIdx.x * blockDim.x + threadIdx.x;   // (bh, s, i8)
    int i8 = t & 3;
    int s  = (t >> 2) & (SS - 1);
    int bh = t >> 13;
    int h = bh & (NHEADS - 1), b = bh >> 4;

    const float* yp = y + ((size_t)(b * SS + s)) * DM + h * DHEAD + i8 * 8;
    float4 a0 = *reinterpret_cast<const float4*>(yp);
    float4 a1 = *reinterpret_cast<const float4*>(yp + 4);
    float4 b0 = *reinterpret_cast<const float4*>(yp + 32);
    float4 b1 = *reinterpret_cast<const float4*>(yp + 36);
    float u0[8] = {a0.x, a0.y, a0.z, a0.w, a1.x, a1.y, a1.z, a1.w};
    float u1[8] = {b0.x, b0.y, b0.z, b0.w, b1.x, b1.y, b1.z, b1.w};
    float lo[8], hi[8];
#pragma unroll
    for (int j = 0; j < 8; j++) {
        int i = i8 * 8 + j;
        float freq = __expf(-(float)i * LN1E4_D32);
        float th = (float)s * freq;
        float cv = cosf(th), sv = sinf(th);   // precise: feeds f32 output directly
        lo[j] = u0[j] * cv - u1[j] * sv;
        hi[j] = u1[j] * cv + u0[j] * sv;
    }
    float* op = kout + ((size_t)bh * SS + s) * DHEAD + i8 * 8;
    *reinterpret_cast<float4*>(op)      = (float4){lo[0], lo[1], lo[2], lo[3]};
    *reinterpret_cast<float4*>(op + 4)  = (float4){lo[4], lo[5], lo[6], lo[7]};
    *reinterpret_cast<float4*>(op + 32) = (float4){hi[0], hi[1], hi[2], hi[3]};
    *reinterpret_cast<float4*>(op + 36) = (float4){hi[4], hi[5], hi[6], hi[7]};

    // roped bf16 swizzled attn K tiles
    ushort_t* kb = khb + ((size_t)bh * 32 + (s >> 6)) * 4096 + (s & 63) * 64;
    short8 vlo, vhi;
#pragma unroll
    for (int j = 0; j < 8; j++) { vlo[j] = (short)f2bf(lo[j]); vhi[j] = (short)f2bf(hi[j]); }
    *reinterpret_cast<short8*>(kb + ((i8 ^ (s & 7)) << 3))       = vlo;
    *reinterpret_cast<short8*>(kb + (((i8 + 4) ^ (s & 7)) << 3)) = vhi;

    // un-roped bf16 y GEMM tiles (same swizzle as cvt_tile_kernel)
    int rowm = b * SS + s;                 // 0..4095
    int rowin = rowm & 127, rbm = rowm >> 7;
    int g = i8 ^ ((rowin >> 1) & 3);       // kk>>3 == i8 for both lo and hi chunks
    ushort_t* yt = yb + ((size_t)(rbm * 32 + h * 2)) * 4096 + rowin * 32 + (g << 3);
    short8 ulo, uhi;
#pragma unroll
    for (int j = 0; j < 8; j++) { ulo[j] = (short)f2bf(u0[j]); uhi[j] = (short)f2bf(u1[j]); }
    *reinterpret_cast<short8*>(yt)        = ulo;   // kb = h*2
    *reinterpret_cast<short8*>(yt + 4096) = uhi;   // kb = h*2+1
}

// ---------------- 3 projection GEMMs: bf16 tiled inputs, global_load_lds double-buffer ----
// z=0: Q = rope(x*wq^T) -> heads-layout bf16 ; z=1: V = y*wv^T -> pre-transposed swizzled
// V^T tiles ; z=2: V1 = x*wo^T -> heads-layout bf16
__global__ __launch_bounds__(256, 2) void gemm3_kernel(
        const ushort_t* __restrict__ xb, const ushort_t* __restrict__ yb,
        const ushort_t* __restrict__ wqb, const ushort_t* __restrict__ wvb,
        const ushort_t* __restrict__ wob,
        ushort_t* __restrict__ qh, ushort_t* __restrict__ vt, ushort_t* __restrict__ v1h) {
    __shared__ __align__(16) char smem[34816];
    ushort_t* As = (ushort_t*)smem;              // [2][4096] double buffer
    ushort_t* Bs = (ushort_t*)(smem + 16384);    // [2][4096]
    ushort_t (*Ct)[136] = (ushort_t(*)[136])smem;   // epilogue reuse

    int bid = blockIdx.x;
    int xcd = bid & 7;
    int s_  = bid >> 3;
    int zo  = s_ >> 5;
    int z   = (zo == 0) ? 0 : (zo == 1 ? 2 : 1);
    int t_  = s_ & 31;
    int n0  = (t_ >> 2) * 128;
    int m0  = (xcd * 4 + (t_ & 3)) * 128;

    const ushort_t* A = (z == 1) ? yb : xb;
    const ushort_t* W = (z == 0) ? wqb : (z == 1 ? wvb : wob);
    ushort_t* O = (z == 0) ? qh : (z == 1 ? vt : v1h);

    const ushort_t* Atl = A + (size_t)(m0 >> 7) * 32 * 4096;
    const ushort_t* Wtl = W + (size_t)(n0 >> 7) * 32 * 4096;

    int tid = threadIdx.x;
    int wave = tid >> 6, lane = tid & 63, quad = lane >> 4, l15 = lane & 15;
    int wr = (wave >> 1) * 64, wc = (wave & 1) * 64;

    int gi0 = tid * 8, gi1 = (256 + tid) * 8;                 // per-lane global chunks
    int li0 = (tid & 192) * 8, li1 = (256 + (tid & 192)) * 8; // wave-uniform LDS bases

    // swizzled fragment LDS offsets (conflict-free ds_read_b128)
    int aoff[4], boff[4];
#pragma unroll
    for (int mi = 0; mi < 4; mi++) {
        int row = wr + mi * 16 + l15;
        aoff[mi] = row * 32 + ((quad ^ ((row >> 1) & 3)) << 3);
    }
#pragma unroll
    for (int ni = 0; ni < 4; ni++) {
        int row = wc + ni * 16 + l15;
        boff[ni] = row * 32 + ((quad ^ ((row >> 1) & 3)) << 3);
    }

    float4v acc[4][4];
#pragma unroll
    for (int a = 0; a < 4; a++)
#pragma unroll
        for (int b = 0; b < 4; b++)
            acc[a][b] = (float4v){0.f, 0.f, 0.f, 0.f};

    // prologue: stage kb=0 into buffer 0
    gload16(Atl + gi0, As + li0); gload16(Atl + gi1, As + li1);
    gload16(Wtl + gi0, Bs + li0); gload16(Wtl + gi1, Bs + li1);
    int cur = 0;

    for (int kb = 0; kb < 32; kb++) {
        __syncthreads();   // drains vmcnt -> buf[cur] ready; prior reads of buf[cur^1] done
        if (kb + 1 < 32) {
            const ushort_t* at = Atl + (size_t)(kb + 1) * 4096;
            const ushort_t* wt = Wtl + (size_t)(kb + 1) * 4096;
            int nb = (cur ^ 1) * 4096;
            gload16(at + gi0, As + nb + li0); gload16(at + gi1, As + nb + li1);
            gload16(wt + gi0, Bs + nb + li0); gload16(wt + gi1, Bs + nb + li1);
        }
        const ushort_t* Ac = As + cur * 4096;
        const ushort_t* Bc = Bs + cur * 4096;
        short8 af[4], bfr[4];
#pragma unroll
        for (int mi = 0; mi < 4; mi++)
            af[mi] = *reinterpret_cast<const short8*>(&Ac[aoff[mi]]);
#pragma unroll
        for (int ni = 0; ni < 4; ni++)
            bfr[ni] = *reinterpret_cast<const short8*>(&Bc[boff[ni]]);
#pragma unroll
        for (int mi = 0; mi < 4; mi++)
#pragma unroll
            for (int ni = 0; ni < 4; ni++)
                acc[mi][ni] = __builtin_amdgcn_mfma_f32_16x16x32_bf16(af[mi], bfr[ni], acc[mi][ni], 0, 0, 0);
        cur ^= 1;
    }

    if (z == 0) {
#pragma unroll
        for (int mi = 0; mi < 4; mi++)
#pragma unroll
            for (int r = 0; r < 4; r++) {
                int m = m0 + wr + mi * 16 + quad * 4 + r;
                float pos = (float)(m & (SS - 1));
#pragma unroll
                for (int ni = 0; ni < 2; ni++) {
                    int d = ni * 16 + l15;
                    float f = __expf(-(float)d * LN1E4_D32);
                    float th = pos * f;
                    float cv, sv;
                    __sincosf(th, &sv, &cv);
                    float u0 = acc[mi][ni][r], u1 = acc[mi][ni + 2][r];
                    acc[mi][ni][r]     = u0 * cv - u1 * sv;
                    acc[mi][ni + 2][r] = u1 * cv + u0 * sv;
                }
            }
    }

    __syncthreads();
#pragma unroll
    for (int mi = 0; mi < 4; mi++)
#pragma unroll
        for (int ni = 0; ni < 4; ni++) {
            int col = wc + ni * 16 + l15;
#pragma unroll
            for (int r = 0; r < 4; r++)
                Ct[wr + mi * 16 + quad * 4 + r][col] = f2bf(acc[mi][ni][r]);
        }
    __syncthreads();
    int h0 = n0 >> 6;
    if (z == 1) {
        // V^T swizzled tile write: element (key, dh) -> dh*64 + (((key&63)>>3 ^ (dh&7))<<3) + (key&7)
        int b = m0 >> 11;
        int s0 = m0 & (SS - 1);
#pragma unroll
        for (int it = 0; it < 8; it++) {
            int c = it * 256 + tid;            // [0,2048) chunks of 16B
            int dh  = c & 63;
            int k16 = (c >> 6) & 15;
            int hh  = c >> 10;
            short8 v;
#pragma unroll
            for (int e = 0; e < 8; e++)
                v[e] = (short)Ct[k16 * 8 + e][hh * 64 + dh];
            int kt = (s0 >> 6) + (k16 >> 3);
            size_t off = ((size_t)((b * NHEADS + h0 + hh) * 32 + kt)) * 4096
                       + dh * 64 + (((k16 & 7) ^ (dh & 7)) << 3);
            *reinterpret_cast<short8*>(&O[off]) = v;
        }
    } else {
#pragma unroll
        for (int it = 0; it < 8; it++) {
            int c = it * 256 + tid;
            int o = c >> 3, j = c & 7;
            int hh = o >> 7, mr = o & 127;
            int m = m0 + mr, b = m >> 11, si = m & (SS - 1);
            uint4 v = *reinterpret_cast<const uint4*>(&Ct[mr][hh * 64 + j * 8]);
            *reinterpret_cast<uint4*>(
                &O[((size_t)((b * NHEADS + h0 + hh) * SS + si)) * DHEAD + j * 8]) = v;
        }
    }
}

// ---------------- flash attention: pre-formatted bf16 K / V^T tiles, async double-buffered
// staging via global_load_lds, ONE barrier per tile (Ps/sdiag are per-wave -> no block sync).
__global__ __launch_bounds__(256, 2) void attn_kernel(
        const ushort_t* __restrict__ qh, const float* __restrict__ kf32,
        const ushort_t* __restrict__ khb, const ushort_t* __restrict__ vtb,
        const ushort_t* __restrict__ v1h, float* __restrict__ out) {
    __shared__ __align__(16) ushort_t Ks[2][4096];   // [key][dh] swizzled, 8KB per buffer
    __shared__ __align__(16) ushort_t Vt[2][4096];   // [dh][key] swizzled
    __shared__ ushort_t Ps[4][16][68];               // per-wave P round-trip [q][key]
    __shared__ float sdiag[4][16];

    int bid = blockIdx.x;
    int bh = (bid & 7) * 4 + ((bid >> 3) & 3);
    int qb = 31 - (bid >> 5);
    int q0 = qb * 64;

    int tid = threadIdx.x, wave = tid >> 6, lane = tid & 63, quad = lane >> 4, l15 = lane & 15;
    int q0w = q0 + wave * 16;
    const ushort_t* qp  = qh  + (size_t)bh * SS * DHEAD;
    const float*    kp  = kf32 + (size_t)bh * SS * DHEAD;
    const ushort_t* v1p = v1h + (size_t)bh * SS * DHEAD;
    const ushort_t* ktb = khb + (size_t)bh * 32 * 4096;
    const ushort_t* vtt = vtb + (size_t)bh * 32 * 4096;

    short8 qf[2];
    qf[0] = *reinterpret_cast<const short8*>(&qp[(q0w + l15) * DHEAD + quad * 8]);
    qf[1] = *reinterpret_cast<const short8*>(&qp[(q0w + l15) * DHEAD + 32 + quad * 8]);

    float4v Oa[4];
#pragma unroll
    for (int t = 0; t < 4; t++) Oa[t] = (float4v){0.f, 0.f, 0.f, 0.f};
    float lsum[4] = {0.f, 0.f, 0.f, 0.f};

    int gi0 = tid * 8, gi1 = (256 + tid) * 8;
    int li0 = (tid & 192) * 8, li1 = (256 + (tid & 192)) * 8;

    int ntiles = qb + 1;
    gload16(ktb + gi0, &Ks[0][li0]); gload16(ktb + gi1, &Ks[0][li1]);
    gload16(vtt + gi0, &Vt[0][li0]); gload16(vtt + gi1, &Vt[0][li1]);
    int cur = 0;

    for (int kt = 0; kt < ntiles; kt++) {
        __syncthreads();   // drains vmcnt -> buf[cur] ready; prior reads of buf[cur^1] done
        if (kt + 1 < ntiles) {
            const ushort_t* gk = ktb + (size_t)(kt + 1) * 4096;
            const ushort_t* gv = vtt + (size_t)(kt + 1) * 4096;
            int nb = cur ^ 1;
            gload16(gk + gi0, &Ks[nb][li0]); gload16(gk + gi1, &Ks[nb][li1]);
            gload16(gv + gi0, &Vt[nb][li0]); gload16(gv + gi1, &Vt[nb][li1]);
        }
        const ushort_t* Kc = Ks[cur];
        const ushort_t* Vc = Vt[cur];

        float4v sa[4];
#pragma unroll
        for (int t2 = 0; t2 < 4; t2++) sa[t2] = (float4v){0.f, 0.f, 0.f, 0.f};
#pragma unroll
        for (int t2 = 0; t2 < 4; t2++) {
            int key = t2 * 16 + l15;
            int ro = key * 64, sw = key & 7;
#pragma unroll
            for (int half = 0; half < 2; half++) {
                short8 kf = *reinterpret_cast<const short8*>(&Kc[ro + (((half * 4 + quad) ^ sw) << 3)]);
                sa[t2] = __builtin_amdgcn_mfma_f32_16x16x32_bf16(qf[half], kf, sa[t2], 0, 0, 0);
            }
        }

        // softmax, static max (safe: |s|<~2.5), per-lane partial l
        int kbase = kt * 64;
#pragma unroll
        for (int r = 0; r < 4; r++) {
            int query = q0w + quad * 4 + r;
#pragma unroll
            for (int t2 = 0; t2 < 4; t2++) {
                int key = kbase + t2 * 16 + l15;
                float p = (key <= query) ? __expf(sa[t2][r] * 0.125f) : 0.f;
                Ps[wave][quad * 4 + r][t2 * 16 + l15] = f2bf(p);
                lsum[r] += p;
            }
        }
        // Ps is per-wave: compiler-inserted lgkmcnt orders write->read, no block barrier
        short8 pf0 = *reinterpret_cast<const short8*>(&Ps[wave][l15][quad * 8]);
        short8 pf1 = *reinterpret_cast<const short8*>(&Ps[wave][l15][32 + quad * 8]);
#pragma unroll
        for (int t = 0; t < 4; t++) {
            int dh = t * 16 + l15;
            int ro = dh * 64, sw = dh & 7;
            short8 vf0 = *reinterpret_cast<const short8*>(&Vc[ro + ((quad ^ sw) << 3)]);
            short8 vf1 = *reinterpret_cast<const short8*>(&Vc[ro + (((4 + quad) ^ sw) << 3)]);
            Oa[t] = __builtin_amdgcn_mfma_f32_16x16x32_bf16(pf0, vf0, Oa[t], 0, 0, 0);
            Oa[t] = __builtin_amdgcn_mfma_f32_16x16x32_bf16(pf1, vf1, Oa[t], 0, 0, 0);
        }
        cur ^= 1;
    }

    // diagonal extra key: s_d = q[i] . rope(k_roped[i]) / 8, value v1[i]
    {
        int sk = q0w + l15;
        const float* krow = kp + (size_t)sk * DHEAD;
        short8 k1lo, k1hi;
#pragma unroll
        for (int j = 0; j < 8; j++) {
            int d = quad * 8 + j;
            float f = __expf(-(float)d * LN1E4_D32);
            float th = (float)sk * f;
            float cv, sv;
            __sincosf(th, &sv, &cv);
            float a = krow[d], b2 = krow[d + 32];
            k1lo[j] = (short)f2bf(a * cv - b2 * sv);
            k1hi[j] = (short)f2bf(b2 * cv + a * sv);
        }
        float4v sd4 = (float4v){0.f, 0.f, 0.f, 0.f};
        sd4 = __builtin_amdgcn_mfma_f32_16x16x32_bf16(qf[0], k1lo, sd4, 0, 0, 0);
        sd4 = __builtin_amdgcn_mfma_f32_16x16x32_bf16(qf[1], k1hi, sd4, 0, 0, 0);
#pragma unroll
        for (int r = 0; r < 4; r++)
            if (l15 == quad * 4 + r) sdiag[wave][l15] = sd4[r] * 0.125f;
        __syncthreads();

        int b = bh >> 4, h = bh & (NHEADS - 1);
#pragma unroll
        for (int r = 0; r < 4; r++) {
            float ls = lsum[r];
#pragma unroll
            for (int off = 1; off < 16; off <<= 1) ls += __shfl_xor(ls, off);
            float pd = __expf(sdiag[wave][quad * 4 + r]);
            int query = q0w + quad * 4 + r;
            float linv = 1.f / (ls + pd);
#pragma unroll
            for (int t = 0; t < 4; t++) {
                float v1v = bf2f(v1p[query * DHEAD + t * 16 + l15]);
                float o = (Oa[t][r] + pd * v1v) * linv;
                out[(b * SS + query) * DM + h * DHEAD + t * 16 + l15] = o;
            }
        }
    }
}

extern "C" void kernel_launch(void* const* d_in, const int* in_sizes, int n_in,
                              void* d_out, int out_size, void* d_ws, size_t ws_size,
                              hipStream_t stream) {
    const float* x  = (const float*)d_in[0];
    const float* y  = (const float*)d_in[1];
    const float* wq = (const float*)d_in[2];
    // d_in[3] = wk is unused by the reference
    const float* wv = (const float*)d_in[4];
    const float* wo = (const float*)d_in[5];
    float* outp  = (float*)d_out;                       // output 0: (2,2048,1024) f32
    float* k_out = outp + (size_t)BB * SS * DM;         // output 1: roped K (2,16,2048,64) f32

    char* ws = (char*)d_ws;
    ushort_t* vtb = (ushort_t*)(ws);                  // 8 MB  V^T swizzled attn tiles
    ushort_t* v1b = (ushort_t*)(ws + (8ull  << 20));  // 8 MB  V1 heads-layout bf16
    ushort_t* qhb = (ushort_t*)(ws + (16ull << 20));  // 8 MB  Q heads-layout bf16
    ushort_t* khb = (ushort_t*)(ws + (24ull << 20));  // 8 MB  roped-K swizzled attn tiles
    ushort_t* xb  = (ushort_t*)(ws + (32ull << 20));  // 8 MB  x bf16 GEMM tiles
    ushort_t* yb  = (ushort_t*)(ws + (40ull << 20));  // 8 MB  y bf16 GEMM tiles
    ushort_t* wqb = (ushort_t*)(ws + (48ull << 20));  // 2 MB
    ushort_t* wvb = (ushort_t*)(ws + (50ull << 20));  // 2 MB
    ushort_t* wob = (ushort_t*)(ws + (52ull << 20));  // 2 MB  (total 54 MB)

    cvt_tile_kernel<<<3584, 256, 0, stream>>>(x, wq, wv, wo, xb, wqb, wvb, wob);
    rope_k_kernel<<<1024, 256, 0, stream>>>(y, k_out, khb, yb);
    gemm3_kernel<<<768, 256, 0, stream>>>(xb, yb, wqb, wvb, wob, qhb, vtb, v1b);
    attn_kernel<<<1024, 256, 0, stream>>>(qhb, k_out, khb, vtb, v1b, outp);
}

// Round 3
// 176.128 us; speedup vs baseline: 1.3234x; 1.0484x over previous
//
#include <hip/hip_runtime.h>

#define DM 1024
#define NHEADS 16
#define DHEAD 64
#define BB 2
#define SS 2048
#define BH (BB*NHEADS)

typedef __attribute__((ext_vector_type(8))) short short8;
typedef __attribute__((ext_vector_type(4))) float float4v;
typedef unsigned short ushort_t;

#define LN1E4_D32 0.28782313662425572f   // ln(10000)/32

static __device__ __forceinline__ unsigned short f2bf(float f) {
    union { float f; unsigned u; } v; v.f = f;
    unsigned r = v.u + 0x7fffu + ((v.u >> 16) & 1u);
    return (unsigned short)(r >> 16);
}
static __device__ __forceinline__ float bf2f(unsigned short u) {
    union { float f; unsigned u; } v; v.u = ((unsigned)u) << 16;
    return v.f;
}
// packed f32x2 -> bf16x2 (RNE, bit-identical to f2bf)
static __device__ __forceinline__ unsigned cvtpk_bf16(float lo, float hi) {
    unsigned r;
    asm("v_cvt_pk_bf16_f32 %0, %1, %2" : "=v"(r) : "v"(lo), "v"(hi));
    return r;
}

// async global->LDS 16B copy: lds dest is wave-uniform base + lane*16
static __device__ __forceinline__ void gload16(const ushort_t* g, ushort_t* l) {
    __builtin_amdgcn_global_load_lds(
        (const __attribute__((address_space(1))) void*)g,
        (__attribute__((address_space(3))) void*)l, 16, 0, 0);
}

// ---------------- prepass: f32 -> bf16 pre-swizzled 128x32 GEMM tiles ----------------
__global__ __launch_bounds__(256) void cvt_tile_kernel(
        const float* __restrict__ x, const float* __restrict__ wq,
        const float* __restrict__ wv, const float* __restrict__ wo,
        ushort_t* __restrict__ xb, ushort_t* __restrict__ wqb,
        ushort_t* __restrict__ wvb, ushort_t* __restrict__ wob) {
    int C = blockIdx.x * 256 + threadIdx.x;
    int c  = C & 511;
    int tl = C >> 9;
    int rb = tl >> 5, kb = tl & 31;
    const float* src; ushort_t* dst; int r0;
    if (rb < 32)      { src = x;  r0 = rb * 128;        dst = xb  + (size_t)tl * 4096; }
    else if (rb < 40) { src = wq; r0 = (rb - 32) * 128; dst = wqb + (size_t)(((rb - 32) * 32) + kb) * 4096; }
    else if (rb < 48) { src = wv; r0 = (rb - 40) * 128; dst = wvb + (size_t)(((rb - 40) * 32) + kb) * 4096; }
    else              { src = wo; r0 = (rb - 48) * 128; dst = wob + (size_t)(((rb - 48) * 32) + kb) * 4096; }
    int row = c >> 2, g = c & 3;
    int kk3 = g ^ ((row >> 1) & 3);
    const float* s = src + (size_t)(r0 + row) * DM + kb * 32 + kk3 * 8;
    float4 a0 = *reinterpret_cast<const float4*>(s);
    float4 a1 = *reinterpret_cast<const float4*>(s + 4);
    short8 v;
    v[0] = (short)f2bf(a0.x); v[1] = (short)f2bf(a0.y);
    v[2] = (short)f2bf(a0.z); v[3] = (short)f2bf(a0.w);
    v[4] = (short)f2bf(a1.x); v[5] = (short)f2bf(a1.y);
    v[6] = (short)f2bf(a1.z); v[7] = (short)f2bf(a1.w);
    *reinterpret_cast<short8*>(dst + c * 8) = v;
}

// ---------------- RoPE on K = heads(y): f32 roped K (output 1) + bf16 swizzled attn tiles
// + un-roped bf16 y GEMM tiles (A-operand of the V projection) ----------------
__global__ __launch_bounds__(256) void rope_k_kernel(const float* __restrict__ y,
        float* __restrict__ kout, ushort_t* __restrict__ khb, ushort_t* __restrict__ yb) {
    int t = blockIdx.x * blockDim.x + threadIdx.x;
    int i8 = t & 3;
    int s  = (t >> 2) & (SS - 1);
    int bh = t >> 13;
    int h = bh & (NHEADS - 1), b = bh >> 4;

    const float* yp = y + ((size_t)(b * SS + s)) * DM + h * DHEAD + i8 * 8;
    float4 a0 = *reinterpret_cast<const float4*>(yp);
    float4 a1 = *reinterpret_cast<const float4*>(yp + 4);
    float4 b0 = *reinterpret_cast<const float4*>(yp + 32);
    float4 b1 = *reinterpret_cast<const float4*>(yp + 36);
    float u0[8] = {a0.x, a0.y, a0.z, a0.w, a1.x, a1.y, a1.z, a1.w};
    float u1[8] = {b0.x, b0.y, b0.z, b0.w, b1.x, b1.y, b1.z, b1.w};
    float lo[8], hi[8];
#pragma unroll
    for (int j = 0; j < 8; j++) {
        int i = i8 * 8 + j;
        float freq = __expf(-(float)i * LN1E4_D32);
        float th = (float)s * freq;
        float cv = cosf(th), sv = sinf(th);   // precise: feeds f32 output directly
        lo[j] = u0[j] * cv - u1[j] * sv;
        hi[j] = u1[j] * cv + u0[j] * sv;
    }
    float* op = kout + ((size_t)bh * SS + s) * DHEAD + i8 * 8;
    *reinterpret_cast<float4*>(op)      = (float4){lo[0], lo[1], lo[2], lo[3]};
    *reinterpret_cast<float4*>(op + 4)  = (float4){lo[4], lo[5], lo[6], lo[7]};
    *reinterpret_cast<float4*>(op + 32) = (float4){hi[0], hi[1], hi[2], hi[3]};
    *reinterpret_cast<float4*>(op + 36) = (float4){hi[4], hi[5], hi[6], hi[7]};

    // roped bf16 swizzled attn K tiles
    ushort_t* kb = khb + ((size_t)bh * 32 + (s >> 6)) * 4096 + (s & 63) * 64;
    short8 vlo, vhi;
#pragma unroll
    for (int j = 0; j < 8; j++) { vlo[j] = (short)f2bf(lo[j]); vhi[j] = (short)f2bf(hi[j]); }
    *reinterpret_cast<short8*>(kb + ((i8 ^ (s & 7)) << 3))       = vlo;
    *reinterpret_cast<short8*>(kb + (((i8 + 4) ^ (s & 7)) << 3)) = vhi;

    // un-roped bf16 y GEMM tiles (same swizzle as cvt_tile_kernel)
    int rowm = b * SS + s;
    int rowin = rowm & 127, rbm = rowm >> 7;
    int g = i8 ^ ((rowin >> 1) & 3);
    ushort_t* yt = yb + ((size_t)(rbm * 32 + h * 2)) * 4096 + rowin * 32 + (g << 3);
    short8 ulo, uhi;
#pragma unroll
    for (int j = 0; j < 8; j++) { ulo[j] = (short)f2bf(u0[j]); uhi[j] = (short)f2bf(u1[j]); }
    *reinterpret_cast<short8*>(yt)        = ulo;   // kb = h*2
    *reinterpret_cast<short8*>(yt + 4096) = uhi;   // kb = h*2+1
}

// ---------------- 3 projection GEMMs: bf16 tiled inputs, global_load_lds double-buffer ----
__global__ __launch_bounds__(256, 2) void gemm3_kernel(
        const ushort_t* __restrict__ xb, const ushort_t* __restrict__ yb,
        const ushort_t* __restrict__ wqb, const ushort_t* __restrict__ wvb,
        const ushort_t* __restrict__ wob,
        ushort_t* __restrict__ qh, ushort_t* __restrict__ vt, ushort_t* __restrict__ v1h) {
    __shared__ __align__(16) char smem[34816];
    ushort_t* As = (ushort_t*)smem;              // [2][4096] double buffer
    ushort_t* Bs = (ushort_t*)(smem + 16384);    // [2][4096]
    ushort_t (*Ct)[136] = (ushort_t(*)[136])smem;   // epilogue reuse

    int bid = blockIdx.x;
    int xcd = bid & 7;
    int s_  = bid >> 3;
    int zo  = s_ >> 5;
    int z   = (zo == 0) ? 0 : (zo == 1 ? 2 : 1);
    int t_  = s_ & 31;
    int n0  = (t_ >> 2) * 128;
    int m0  = (xcd * 4 + (t_ & 3)) * 128;

    const ushort_t* A = (z == 1) ? yb : xb;
    const ushort_t* W = (z == 0) ? wqb : (z == 1 ? wvb : wob);
    ushort_t* O = (z == 0) ? qh : (z == 1 ? vt : v1h);

    const ushort_t* Atl = A + (size_t)(m0 >> 7) * 32 * 4096;
    const ushort_t* Wtl = W + (size_t)(n0 >> 7) * 32 * 4096;

    int tid = threadIdx.x;
    int wave = tid >> 6, lane = tid & 63, quad = lane >> 4, l15 = lane & 15;
    int wr = (wave >> 1) * 64, wc = (wave & 1) * 64;

    int gi0 = tid * 8, gi1 = (256 + tid) * 8;
    int li0 = (tid & 192) * 8, li1 = (256 + (tid & 192)) * 8;

    int aoff[4], boff[4];
#pragma unroll
    for (int mi = 0; mi < 4; mi++) {
        int row = wr + mi * 16 + l15;
        aoff[mi] = row * 32 + ((quad ^ ((row >> 1) & 3)) << 3);
    }
#pragma unroll
    for (int ni = 0; ni < 4; ni++) {
        int row = wc + ni * 16 + l15;
        boff[ni] = row * 32 + ((quad ^ ((row >> 1) & 3)) << 3);
    }

    float4v acc[4][4];
#pragma unroll
    for (int a = 0; a < 4; a++)
#pragma unroll
        for (int b = 0; b < 4; b++)
            acc[a][b] = (float4v){0.f, 0.f, 0.f, 0.f};

    gload16(Atl + gi0, As + li0); gload16(Atl + gi1, As + li1);
    gload16(Wtl + gi0, Bs + li0); gload16(Wtl + gi1, Bs + li1);
    int cur = 0;

    for (int kb = 0; kb < 32; kb++) {
        __syncthreads();
        if (kb + 1 < 32) {
            const ushort_t* at = Atl + (size_t)(kb + 1) * 4096;
            const ushort_t* wt = Wtl + (size_t)(kb + 1) * 4096;
            int nb = (cur ^ 1) * 4096;
            gload16(at + gi0, As + nb + li0); gload16(at + gi1, As + nb + li1);
            gload16(wt + gi0, Bs + nb + li0); gload16(wt + gi1, Bs + nb + li1);
        }
        const ushort_t* Ac = As + cur * 4096;
        const ushort_t* Bc = Bs + cur * 4096;
        short8 af[4], bfr[4];
#pragma unroll
        for (int mi = 0; mi < 4; mi++)
            af[mi] = *reinterpret_cast<const short8*>(&Ac[aoff[mi]]);
#pragma unroll
        for (int ni = 0; ni < 4; ni++)
            bfr[ni] = *reinterpret_cast<const short8*>(&Bc[boff[ni]]);
#pragma unroll
        for (int mi = 0; mi < 4; mi++)
#pragma unroll
            for (int ni = 0; ni < 4; ni++)
                acc[mi][ni] = __builtin_amdgcn_mfma_f32_16x16x32_bf16(af[mi], bfr[ni], acc[mi][ni], 0, 0, 0);
        cur ^= 1;
    }

    if (z == 0) {
#pragma unroll
        for (int mi = 0; mi < 4; mi++)
#pragma unroll
            for (int r = 0; r < 4; r++) {
                int m = m0 + wr + mi * 16 + quad * 4 + r;
                float pos = (float)(m & (SS - 1));
#pragma unroll
                for (int ni = 0; ni < 2; ni++) {
                    int d = ni * 16 + l15;
                    float f = __expf(-(float)d * LN1E4_D32);
                    float th = pos * f;
                    float cv, sv;
                    __sincosf(th, &sv, &cv);
                    float u0 = acc[mi][ni][r], u1 = acc[mi][ni + 2][r];
                    acc[mi][ni][r]     = u0 * cv - u1 * sv;
                    acc[mi][ni + 2][r] = u1 * cv + u0 * sv;
                }
            }
    }

    __syncthreads();
#pragma unroll
    for (int mi = 0; mi < 4; mi++)
#pragma unroll
        for (int ni = 0; ni < 4; ni++) {
            int col = wc + ni * 16 + l15;
#pragma unroll
            for (int r = 0; r < 4; r++)
                Ct[wr + mi * 16 + quad * 4 + r][col] = f2bf(acc[mi][ni][r]);
        }
    __syncthreads();
    int h0 = n0 >> 6;
    if (z == 1) {
        int b = m0 >> 11;
        int s0 = m0 & (SS - 1);
#pragma unroll
        for (int it = 0; it < 8; it++) {
            int c = it * 256 + tid;
            int dh  = c & 63;
            int k16 = (c >> 6) & 15;
            int hh  = c >> 10;
            short8 v;
#pragma unroll
            for (int e = 0; e < 8; e++)
                v[e] = (short)Ct[k16 * 8 + e][hh * 64 + dh];
            int kt = (s0 >> 6) + (k16 >> 3);
            size_t off = ((size_t)((b * NHEADS + h0 + hh) * 32 + kt)) * 4096
                       + dh * 64 + (((k16 & 7) ^ (dh & 7)) << 3);
            *reinterpret_cast<short8*>(&O[off]) = v;
        }
    } else {
#pragma unroll
        for (int it = 0; it < 8; it++) {
            int c = it * 256 + tid;
            int o = c >> 3, j = c & 7;
            int hh = o >> 7, mr = o & 127;
            int m = m0 + mr, b = m >> 11, si = m & (SS - 1);
            uint4 v = *reinterpret_cast<const uint4*>(&Ct[mr][hh * 64 + j * 8]);
            *reinterpret_cast<uint4*>(
                &O[((size_t)((b * NHEADS + h0 + hh) * SS + si)) * DHEAD + j * 8]) = v;
        }
    }
}

// ---------------- flash attention: swapped QK^T (S^T layout), packed cvt_pk P->bf16,
// mask hoisted to the one diagonal tile, async double-buffered staging, 1 barrier/tile ----
// Swapped mfma(kf,qf): D[key][query] with key=kbase+t2*16+quad*4+r, query=q0w+l15.
// Each lane holds 4 CONSECUTIVE keys for one query -> v_cvt_pk_bf16_f32 pairs + b32 writes.
template<bool MASKED>
static __device__ __forceinline__ void attn_tile(
        const ushort_t* __restrict__ Kc, const ushort_t* __restrict__ Vc, int kbase,
        int quad, int l15, int q0w, const short8* qf,
        ushort_t (*Psw)[70], float4v* Oa, float& lsum) {
    float4v sa[4];
#pragma unroll
    for (int t2 = 0; t2 < 4; t2++) sa[t2] = (float4v){0.f, 0.f, 0.f, 0.f};
#pragma unroll
    for (int t2 = 0; t2 < 4; t2++) {
        int key = t2 * 16 + l15;
        int ro = key * 64, sw = key & 7;
#pragma unroll
        for (int half = 0; half < 2; half++) {
            short8 kf = *reinterpret_cast<const short8*>(&Kc[ro + (((half * 4 + quad) ^ sw) << 3)]);
            sa[t2] = __builtin_amdgcn_mfma_f32_16x16x32_bf16(kf, qf[half], sa[t2], 0, 0, 0);
        }
    }
    int query = q0w + l15;
#pragma unroll
    for (int t2 = 0; t2 < 4; t2++) {
        float p[4];
#pragma unroll
        for (int r = 0; r < 4; r++) {
            float e = __expf(sa[t2][r] * 0.125f);
            if (MASKED) {
                int key = kbase + t2 * 16 + quad * 4 + r;
                p[r] = (key <= query) ? e : 0.f;
            } else {
                p[r] = e;
            }
        }
        lsum += (p[0] + p[1]) + (p[2] + p[3]);
        unsigned w0 = cvtpk_bf16(p[0], p[1]);
        unsigned w1 = cvtpk_bf16(p[2], p[3]);
        *reinterpret_cast<unsigned*>(&Psw[l15][t2 * 16 + quad * 4])     = w0;
        *reinterpret_cast<unsigned*>(&Psw[l15][t2 * 16 + quad * 4 + 2]) = w1;
    }
    // per-wave LDS: compiler-inserted lgkmcnt orders writes before these reads
    short8 pf0 = *reinterpret_cast<const short8*>(&Psw[l15][quad * 8]);
    short8 pf1 = *reinterpret_cast<const short8*>(&Psw[l15][32 + quad * 8]);
#pragma unroll
    for (int t = 0; t < 4; t++) {
        int dh = t * 16 + l15;
        int ro = dh * 64, sw = dh & 7;
        short8 vf0 = *reinterpret_cast<const short8*>(&Vc[ro + ((quad ^ sw) << 3)]);
        short8 vf1 = *reinterpret_cast<const short8*>(&Vc[ro + (((4 + quad) ^ sw) << 3)]);
        Oa[t] = __builtin_amdgcn_mfma_f32_16x16x32_bf16(pf0, vf0, Oa[t], 0, 0, 0);
        Oa[t] = __builtin_amdgcn_mfma_f32_16x16x32_bf16(pf1, vf1, Oa[t], 0, 0, 0);
    }
}

__global__ __launch_bounds__(256, 2) void attn_kernel(
        const ushort_t* __restrict__ qh, const float* __restrict__ kf32,
        const ushort_t* __restrict__ khb, const ushort_t* __restrict__ vtb,
        const ushort_t* __restrict__ v1h, float* __restrict__ out) {
    __shared__ __align__(16) ushort_t Ks[2][4096];   // [key][dh] swizzled
    __shared__ __align__(16) ushort_t Vt[2][4096];   // [dh][key] swizzled
    __shared__ ushort_t Ps[4][16][70];               // per-wave P round-trip [q][key], 70-pad
    __shared__ float sdiag[4][16];
    __shared__ float sred[4][16];

    int bid = blockIdx.x;
    int bh = (bid & 7) * 4 + ((bid >> 3) & 3);
    int qb = 31 - (bid >> 5);
    int q0 = qb * 64;

    int tid = threadIdx.x, wave = tid >> 6, lane = tid & 63, quad = lane >> 4, l15 = lane & 15;
    int q0w = q0 + wave * 16;
    const ushort_t* qp  = qh  + (size_t)bh * SS * DHEAD;
    const float*    kp  = kf32 + (size_t)bh * SS * DHEAD;
    const ushort_t* v1p = v1h + (size_t)bh * SS * DHEAD;
    const ushort_t* ktb = khb + (size_t)bh * 32 * 4096;
    const ushort_t* vtt = vtb + (size_t)bh * 32 * 4096;

    short8 qf[2];
    qf[0] = *reinterpret_cast<const short8*>(&qp[(q0w + l15) * DHEAD + quad * 8]);
    qf[1] = *reinterpret_cast<const short8*>(&qp[(q0w + l15) * DHEAD + 32 + quad * 8]);

    float4v Oa[4];
#pragma unroll
    for (int t = 0; t < 4; t++) Oa[t] = (float4v){0.f, 0.f, 0.f, 0.f};
    float lsum = 0.f;

    int gi0 = tid * 8, gi1 = (256 + tid) * 8;
    int li0 = (tid & 192) * 8, li1 = (256 + (tid & 192)) * 8;

    gload16(ktb + gi0, &Ks[0][li0]); gload16(ktb + gi1, &Ks[0][li1]);
    gload16(vtt + gi0, &Vt[0][li0]); gload16(vtt + gi1, &Vt[0][li1]);
    int cur = 0;

    for (int kt = 0; kt < qb; kt++) {
        __syncthreads();   // drains vmcnt -> buf[cur] ready; prior reads of buf[cur^1] done
        const ushort_t* gk = ktb + (size_t)(kt + 1) * 4096;
        const ushort_t* gv = vtt + (size_t)(kt + 1) * 4096;
        int nb = cur ^ 1;
        gload16(gk + gi0, &Ks[nb][li0]); gload16(gk + gi1, &Ks[nb][li1]);
        gload16(gv + gi0, &Vt[nb][li0]); gload16(gv + gi1, &Vt[nb][li1]);
        attn_tile<false>(Ks[cur], Vt[cur], kt * 64, quad, l15, q0w, qf, Ps[wave], Oa, lsum);
        cur ^= 1;
    }
    __syncthreads();       // last (diagonal) tile ready
    attn_tile<true>(Ks[cur], Vt[cur], qb * 64, quad, l15, q0w, qf, Ps[wave], Oa, lsum);

    // reduce lsum across quads (query = q0w + l15 per lane), stash per-wave
    lsum += __shfl_xor(lsum, 16);
    lsum += __shfl_xor(lsum, 32);
    if (quad == 0) sred[wave][l15] = lsum;

    // diagonal extra key: s_d = q[i] . rope(k_roped[i]) / 8, value v1[i]
    {
        int sk = q0w + l15;
        const float* krow = kp + (size_t)sk * DHEAD;
        short8 k1lo, k1hi;
#pragma unroll
        for (int j = 0; j < 8; j++) {
            int d = quad * 8 + j;
            float f = __expf(-(float)d * LN1E4_D32);
            float th = (float)sk * f;
            float cv, sv;
            __sincosf(th, &sv, &cv);
            float a = krow[d], b2 = krow[d + 32];
            k1lo[j] = (short)f2bf(a * cv - b2 * sv);
            k1hi[j] = (short)f2bf(b2 * cv + a * sv);
        }
        float4v sd4 = (float4v){0.f, 0.f, 0.f, 0.f};
        sd4 = __builtin_amdgcn_mfma_f32_16x16x32_bf16(qf[0], k1lo, sd4, 0, 0, 0);
        sd4 = __builtin_amdgcn_mfma_f32_16x16x32_bf16(qf[1], k1hi, sd4, 0, 0, 0);
#pragma unroll
        for (int r = 0; r < 4; r++)
            if (l15 == quad * 4 + r) sdiag[wave][l15] = sd4[r] * 0.125f;
        __syncthreads();

        int b = bh >> 4, h = bh & (NHEADS - 1);
#pragma unroll
        for (int r = 0; r < 4; r++) {
            float ls = sred[wave][quad * 4 + r];
            float pd = __expf(sdiag[wave][quad * 4 + r]);
            int query = q0w + quad * 4 + r;
            float linv = 1.f / (ls + pd);
#pragma unroll
            for (int t = 0; t < 4; t++) {
                float v1v = bf2f(v1p[query * DHEAD + t * 16 + l15]);
                float o = (Oa[t][r] + pd * v1v) * linv;
                out[(b * SS + query) * DM + h * DHEAD + t * 16 + l15] = o;
            }
        }
    }
}

extern "C" void kernel_launch(void* const* d_in, const int* in_sizes, int n_in,
                              void* d_out, int out_size, void* d_ws, size_t ws_size,
                              hipStream_t stream) {
    const float* x  = (const float*)d_in[0];
    const float* y  = (const float*)d_in[1];
    const float* wq = (const float*)d_in[2];
    // d_in[3] = wk is unused by the reference
    const float* wv = (const float*)d_in[4];
    const float* wo = (const float*)d_in[5];
    float* outp  = (float*)d_out;                       // output 0: (2,2048,1024) f32
    float* k_out = outp + (size_t)BB * SS * DM;         // output 1: roped K (2,16,2048,64) f32

    char* ws = (char*)d_ws;
    ushort_t* vtb = (ushort_t*)(ws);                  // 8 MB  V^T swizzled attn tiles
    ushort_t* v1b = (ushort_t*)(ws + (8ull  << 20));  // 8 MB  V1 heads-layout bf16
    ushort_t* qhb = (ushort_t*)(ws + (16ull << 20));  // 8 MB  Q heads-layout bf16
    ushort_t* khb = (ushort_t*)(ws + (24ull << 20));  // 8 MB  roped-K swizzled attn tiles
    ushort_t* xb  = (ushort_t*)(ws + (32ull << 20));  // 8 MB  x bf16 GEMM tiles
    ushort_t* yb  = (ushort_t*)(ws + (40ull << 20));  // 8 MB  y bf16 GEMM tiles
    ushort_t* wqb = (ushort_t*)(ws + (48ull << 20));  // 2 MB
    ushort_t* wvb = (ushort_t*)(ws + (50ull << 20));  // 2 MB
    ushort_t* wob = (ushort_t*)(ws + (52ull << 20));  // 2 MB  (total 54 MB)

    cvt_tile_kernel<<<3584, 256, 0, stream>>>(x, wq, wv, wo, xb, wqb, wvb, wob);
    rope_k_kernel<<<1024, 256, 0, stream>>>(y, k_out, khb, yb);
    gemm3_kernel<<<768, 256, 0, stream>>>(xb, yb, wqb, wvb, wob, qhb, vtb, v1b);
    attn_kernel<<<1024, 256, 0, stream>>>(qhb, k_out, khb, vtb, v1b, outp);
}

// Round 4
// 175.964 us; speedup vs baseline: 1.3246x; 1.0009x over previous
//
#include <hip/hip_runtime.h>

#define DM 1024
#define NHEADS 16
#define DHEAD 64
#define BB 2
#define SS 2048
#define BH (BB*NHEADS)

typedef __attribute__((ext_vector_type(8))) short short8;
typedef __attribute__((ext_vector_type(4))) float float4v;
typedef unsigned short ushort_t;

#define LN1E4_D32 0.28782313662425572f   // ln(10000)/32

static __device__ __forceinline__ unsigned short f2bf(float f) {
    union { float f; unsigned u; } v; v.f = f;
    unsigned r = v.u + 0x7fffu + ((v.u >> 16) & 1u);
    return (unsigned short)(r >> 16);
}
static __device__ __forceinline__ float bf2f(unsigned short u) {
    union { float f; unsigned u; } v; v.u = ((unsigned)u) << 16;
    return v.f;
}
// packed f32x2 -> bf16x2 (RNE, bit-identical to f2bf)
static __device__ __forceinline__ unsigned cvtpk_bf16(float lo, float hi) {
    unsigned r;
    asm("v_cvt_pk_bf16_f32 %0, %1, %2" : "=v"(r) : "v"(lo), "v"(hi));
    return r;
}

// async global->LDS 16B copy: lds dest is wave-uniform base + lane*16
static __device__ __forceinline__ void gload16(const ushort_t* g, ushort_t* l) {
    __builtin_amdgcn_global_load_lds(
        (const __attribute__((address_space(1))) void*)g,
        (__attribute__((address_space(3))) void*)l, 16, 0, 0);
}

// ---------------- prepass: f32 -> bf16 pre-swizzled 128x32 GEMM tiles ----------------
__global__ __launch_bounds__(256) void cvt_tile_kernel(
        const float* __restrict__ x, const float* __restrict__ wq,
        const float* __restrict__ wv, const float* __restrict__ wo,
        ushort_t* __restrict__ xb, ushort_t* __restrict__ wqb,
        ushort_t* __restrict__ wvb, ushort_t* __restrict__ wob) {
    int C = blockIdx.x * 256 + threadIdx.x;
    int c  = C & 511;
    int tl = C >> 9;
    int rb = tl >> 5, kb = tl & 31;
    const float* src; ushort_t* dst; int r0;
    if (rb < 32)      { src = x;  r0 = rb * 128;        dst = xb  + (size_t)tl * 4096; }
    else if (rb < 40) { src = wq; r0 = (rb - 32) * 128; dst = wqb + (size_t)(((rb - 32) * 32) + kb) * 4096; }
    else if (rb < 48) { src = wv; r0 = (rb - 40) * 128; dst = wvb + (size_t)(((rb - 40) * 32) + kb) * 4096; }
    else              { src = wo; r0 = (rb - 48) * 128; dst = wob + (size_t)(((rb - 48) * 32) + kb) * 4096; }
    int row = c >> 2, g = c & 3;
    int kk3 = g ^ ((row >> 1) & 3);
    const float* s = src + (size_t)(r0 + row) * DM + kb * 32 + kk3 * 8;
    float4 a0 = *reinterpret_cast<const float4*>(s);
    float4 a1 = *reinterpret_cast<const float4*>(s + 4);
    short8 v;
    v[0] = (short)f2bf(a0.x); v[1] = (short)f2bf(a0.y);
    v[2] = (short)f2bf(a0.z); v[3] = (short)f2bf(a0.w);
    v[4] = (short)f2bf(a1.x); v[5] = (short)f2bf(a1.y);
    v[6] = (short)f2bf(a1.z); v[7] = (short)f2bf(a1.w);
    *reinterpret_cast<short8*>(dst + c * 8) = v;
}

// ---------------- RoPE on K = heads(y): f32 roped K (output 1) + bf16 swizzled attn tiles
// + un-roped bf16 y GEMM tiles (A-operand of the V projection) ----------------
__global__ __launch_bounds__(256) void rope_k_kernel(const float* __restrict__ y,
        float* __restrict__ kout, ushort_t* __restrict__ khb, ushort_t* __restrict__ yb) {
    int t = blockIdx.x * blockDim.x + threadIdx.x;
    int i8 = t & 3;
    int s  = (t >> 2) & (SS - 1);
    int bh = t >> 13;
    int h = bh & (NHEADS - 1), b = bh >> 4;

    const float* yp = y + ((size_t)(b * SS + s)) * DM + h * DHEAD + i8 * 8;
    float4 a0 = *reinterpret_cast<const float4*>(yp);
    float4 a1 = *reinterpret_cast<const float4*>(yp + 4);
    float4 b0 = *reinterpret_cast<const float4*>(yp + 32);
    float4 b1 = *reinterpret_cast<const float4*>(yp + 36);
    float u0[8] = {a0.x, a0.y, a0.z, a0.w, a1.x, a1.y, a1.z, a1.w};
    float u1[8] = {b0.x, b0.y, b0.z, b0.w, b1.x, b1.y, b1.z, b1.w};
    float lo[8], hi[8];
#pragma unroll
    for (int j = 0; j < 8; j++) {
        int i = i8 * 8 + j;
        float freq = __expf(-(float)i * LN1E4_D32);
        float th = (float)s * freq;
        float cv = cosf(th), sv = sinf(th);   // precise: feeds f32 output directly
        lo[j] = u0[j] * cv - u1[j] * sv;
        hi[j] = u1[j] * cv + u0[j] * sv;
    }
    float* op = kout + ((size_t)bh * SS + s) * DHEAD + i8 * 8;
    *reinterpret_cast<float4*>(op)      = (float4){lo[0], lo[1], lo[2], lo[3]};
    *reinterpret_cast<float4*>(op + 4)  = (float4){lo[4], lo[5], lo[6], lo[7]};
    *reinterpret_cast<float4*>(op + 32) = (float4){hi[0], hi[1], hi[2], hi[3]};
    *reinterpret_cast<float4*>(op + 36) = (float4){hi[4], hi[5], hi[6], hi[7]};

    // roped bf16 swizzled attn K tiles
    ushort_t* kb = khb + ((size_t)bh * 32 + (s >> 6)) * 4096 + (s & 63) * 64;
    short8 vlo, vhi;
#pragma unroll
    for (int j = 0; j < 8; j++) { vlo[j] = (short)f2bf(lo[j]); vhi[j] = (short)f2bf(hi[j]); }
    *reinterpret_cast<short8*>(kb + ((i8 ^ (s & 7)) << 3))       = vlo;
    *reinterpret_cast<short8*>(kb + (((i8 + 4) ^ (s & 7)) << 3)) = vhi;

    // un-roped bf16 y GEMM tiles (same swizzle as cvt_tile_kernel)
    int rowm = b * SS + s;
    int rowin = rowm & 127, rbm = rowm >> 7;
    int g = i8 ^ ((rowin >> 1) & 3);
    ushort_t* yt = yb + ((size_t)(rbm * 32 + h * 2)) * 4096 + rowin * 32 + (g << 3);
    short8 ulo, uhi;
#pragma unroll
    for (int j = 0; j < 8; j++) { ulo[j] = (short)f2bf(u0[j]); uhi[j] = (short)f2bf(u1[j]); }
    *reinterpret_cast<short8*>(yt)        = ulo;   // kb = h*2
    *reinterpret_cast<short8*>(yt + 4096) = uhi;   // kb = h*2+1
}

// ---------------- 3 projection GEMMs: bf16 tiled inputs, global_load_lds double-buffer ----
__global__ __launch_bounds__(256, 2) void gemm3_kernel(
        const ushort_t* __restrict__ xb, const ushort_t* __restrict__ yb,
        const ushort_t* __restrict__ wqb, const ushort_t* __restrict__ wvb,
        const ushort_t* __restrict__ wob,
        ushort_t* __restrict__ qh, ushort_t* __restrict__ vt, ushort_t* __restrict__ v1h) {
    __shared__ __align__(16) char smem[34816];
    ushort_t* As = (ushort_t*)smem;              // [2][4096] double buffer
    ushort_t* Bs = (ushort_t*)(smem + 16384);    // [2][4096]
    ushort_t (*Ct)[136] = (ushort_t(*)[136])smem;   // epilogue reuse

    int bid = blockIdx.x;
    int xcd = bid & 7;
    int s_  = bid >> 3;
    int zo  = s_ >> 5;
    int z   = (zo == 0) ? 0 : (zo == 1 ? 2 : 1);
    int t_  = s_ & 31;
    int n0  = (t_ >> 2) * 128;
    int m0  = (xcd * 4 + (t_ & 3)) * 128;

    const ushort_t* A = (z == 1) ? yb : xb;
    const ushort_t* W = (z == 0) ? wqb : (z == 1 ? wvb : wob);
    ushort_t* O = (z == 0) ? qh : (z == 1 ? vt : v1h);

    const ushort_t* Atl = A + (size_t)(m0 >> 7) * 32 * 4096;
    const ushort_t* Wtl = W + (size_t)(n0 >> 7) * 32 * 4096;

    int tid = threadIdx.x;
    int wave = tid >> 6, lane = tid & 63, quad = lane >> 4, l15 = lane & 15;
    int wr = (wave >> 1) * 64, wc = (wave & 1) * 64;

    int gi0 = tid * 8, gi1 = (256 + tid) * 8;
    int li0 = (tid & 192) * 8, li1 = (256 + (tid & 192)) * 8;

    int aoff[4], boff[4];
#pragma unroll
    for (int mi = 0; mi < 4; mi++) {
        int row = wr + mi * 16 + l15;
        aoff[mi] = row * 32 + ((quad ^ ((row >> 1) & 3)) << 3);
    }
#pragma unroll
    for (int ni = 0; ni < 4; ni++) {
        int row = wc + ni * 16 + l15;
        boff[ni] = row * 32 + ((quad ^ ((row >> 1) & 3)) << 3);
    }

    float4v acc[4][4];
#pragma unroll
    for (int a = 0; a < 4; a++)
#pragma unroll
        for (int b = 0; b < 4; b++)
            acc[a][b] = (float4v){0.f, 0.f, 0.f, 0.f};

    gload16(Atl + gi0, As + li0); gload16(Atl + gi1, As + li1);
    gload16(Wtl + gi0, Bs + li0); gload16(Wtl + gi1, Bs + li1);
    int cur = 0;

    for (int kb = 0; kb < 32; kb++) {
        __syncthreads();
        if (kb + 1 < 32) {
            const ushort_t* at = Atl + (size_t)(kb + 1) * 4096;
            const ushort_t* wt = Wtl + (size_t)(kb + 1) * 4096;
            int nb = (cur ^ 1) * 4096;
            gload16(at + gi0, As + nb + li0); gload16(at + gi1, As + nb + li1);
            gload16(wt + gi0, Bs + nb + li0); gload16(wt + gi1, Bs + nb + li1);
        }
        const ushort_t* Ac = As + cur * 4096;
        const ushort_t* Bc = Bs + cur * 4096;
        short8 af[4], bfr[4];
#pragma unroll
        for (int mi = 0; mi < 4; mi++)
            af[mi] = *reinterpret_cast<const short8*>(&Ac[aoff[mi]]);
#pragma unroll
        for (int ni = 0; ni < 4; ni++)
            bfr[ni] = *reinterpret_cast<const short8*>(&Bc[boff[ni]]);
#pragma unroll
        for (int mi = 0; mi < 4; mi++)
#pragma unroll
            for (int ni = 0; ni < 4; ni++)
                acc[mi][ni] = __builtin_amdgcn_mfma_f32_16x16x32_bf16(af[mi], bfr[ni], acc[mi][ni], 0, 0, 0);
        cur ^= 1;
    }

    if (z == 0) {
#pragma unroll
        for (int mi = 0; mi < 4; mi++)
#pragma unroll
            for (int r = 0; r < 4; r++) {
                int m = m0 + wr + mi * 16 + quad * 4 + r;
                float pos = (float)(m & (SS - 1));
#pragma unroll
                for (int ni = 0; ni < 2; ni++) {
                    int d = ni * 16 + l15;
                    float f = __expf(-(float)d * LN1E4_D32);
                    float th = pos * f;
                    float cv, sv;
                    __sincosf(th, &sv, &cv);
                    float u0 = acc[mi][ni][r], u1 = acc[mi][ni + 2][r];
                    acc[mi][ni][r]     = u0 * cv - u1 * sv;
                    acc[mi][ni + 2][r] = u1 * cv + u0 * sv;
                }
            }
    }

    __syncthreads();
#pragma unroll
    for (int mi = 0; mi < 4; mi++)
#pragma unroll
        for (int ni = 0; ni < 4; ni++) {
            int col = wc + ni * 16 + l15;
#pragma unroll
            for (int r = 0; r < 4; r++)
                Ct[wr + mi * 16 + quad * 4 + r][col] = f2bf(acc[mi][ni][r]);
        }
    __syncthreads();
    int h0 = n0 >> 6;
    if (z == 1) {
        int b = m0 >> 11;
        int s0 = m0 & (SS - 1);
#pragma unroll
        for (int it = 0; it < 8; it++) {
            int c = it * 256 + tid;
            int dh  = c & 63;
            int k16 = (c >> 6) & 15;
            int hh  = c >> 10;
            short8 v;
#pragma unroll
            for (int e = 0; e < 8; e++)
                v[e] = (short)Ct[k16 * 8 + e][hh * 64 + dh];
            int kt = (s0 >> 6) + (k16 >> 3);
            size_t off = ((size_t)((b * NHEADS + h0 + hh) * 32 + kt)) * 4096
                       + dh * 64 + (((k16 & 7) ^ (dh & 7)) << 3);
            *reinterpret_cast<short8*>(&O[off]) = v;
        }
    } else {
#pragma unroll
        for (int it = 0; it < 8; it++) {
            int c = it * 256 + tid;
            int o = c >> 3, j = c & 7;
            int hh = o >> 7, mr = o & 127;
            int m = m0 + mr, b = m >> 11, si = m & (SS - 1);
            uint4 v = *reinterpret_cast<const uint4*>(&Ct[mr][hh * 64 + j * 8]);
            *reinterpret_cast<uint4*>(
                &O[((size_t)((b * NHEADS + h0 + hh) * SS + si)) * DHEAD + j * 8]) = v;
        }
    }
}

// ---------------- flash attention: 8-wave blocks (128 queries), swapped QK^T (S^T),
// packed cvt_pk P->bf16 via XOR-swizzled per-wave Ps, async double-buffered staging ----
// Ps layout per wave: flat [q=l15][64 keys], 16B chunks XOR-swizzled by (l15&7):
// write chunk (2*t2 + (quad>>1)) ^ (l15&7), read chunk (quad ^ (l15&7)) / ((4+quad) ^ ...).
// 16B-aligned (fixes the old 140B-row misaligned ds_read_b128) and <=2-way on banks.
template<bool MASKED>
static __device__ __forceinline__ void attn_tile(
        const ushort_t* __restrict__ Kc, const ushort_t* __restrict__ Vc, int kbase,
        int quad, int l15, int q0w, const short8* qf,
        ushort_t* __restrict__ Psw, float4v* Oa, float& lsum) {
    float4v sa[4];
#pragma unroll
    for (int t2 = 0; t2 < 4; t2++) sa[t2] = (float4v){0.f, 0.f, 0.f, 0.f};
#pragma unroll
    for (int t2 = 0; t2 < 4; t2++) {
        int key = t2 * 16 + l15;
        int ro = key * 64, sw = key & 7;
#pragma unroll
        for (int half = 0; half < 2; half++) {
            short8 kf = *reinterpret_cast<const short8*>(&Kc[ro + (((half * 4 + quad) ^ sw) << 3)]);
            sa[t2] = __builtin_amdgcn_mfma_f32_16x16x32_bf16(kf, qf[half], sa[t2], 0, 0, 0);
        }
    }
    int query = q0w + l15;
    int swl = l15 & 7;
#pragma unroll
    for (int t2 = 0; t2 < 4; t2++) {
        float p[4];
#pragma unroll
        for (int r = 0; r < 4; r++) {
            float e = __expf(sa[t2][r] * 0.125f);
            if (MASKED) {
                int key = kbase + t2 * 16 + quad * 4 + r;
                p[r] = (key <= query) ? e : 0.f;
            } else {
                p[r] = e;
            }
        }
        lsum += (p[0] + p[1]) + (p[2] + p[3]);
        unsigned w0 = cvtpk_bf16(p[0], p[1]);
        unsigned w1 = cvtpk_bf16(p[2], p[3]);
        int chunk = (((t2 * 2 + (quad >> 1)) ^ swl) << 3) + (quad & 1) * 4;
        *reinterpret_cast<unsigned*>(&Psw[l15 * 64 + chunk])     = w0;
        *reinterpret_cast<unsigned*>(&Psw[l15 * 64 + chunk + 2]) = w1;
    }
    // per-wave LDS: compiler-inserted lgkmcnt orders writes before these reads
    short8 pf0 = *reinterpret_cast<const short8*>(&Psw[l15 * 64 + ((quad ^ swl) << 3)]);
    short8 pf1 = *reinterpret_cast<const short8*>(&Psw[l15 * 64 + (((4 + quad) ^ swl) << 3)]);
#pragma unroll
    for (int t = 0; t < 4; t++) {
        int dh = t * 16 + l15;
        int ro = dh * 64, sw = dh & 7;
        short8 vf0 = *reinterpret_cast<const short8*>(&Vc[ro + ((quad ^ sw) << 3)]);
        short8 vf1 = *reinterpret_cast<const short8*>(&Vc[ro + (((4 + quad) ^ sw) << 3)]);
        Oa[t] = __builtin_amdgcn_mfma_f32_16x16x32_bf16(pf0, vf0, Oa[t], 0, 0, 0);
        Oa[t] = __builtin_amdgcn_mfma_f32_16x16x32_bf16(pf1, vf1, Oa[t], 0, 0, 0);
    }
}

__global__ __launch_bounds__(512, 2) void attn_kernel(
        const ushort_t* __restrict__ qh, const float* __restrict__ kf32,
        const ushort_t* __restrict__ khb, const ushort_t* __restrict__ vtb,
        const ushort_t* __restrict__ v1h, float* __restrict__ out) {
    __shared__ __align__(16) ushort_t Ks[2][4096];   // [key][dh] swizzled
    __shared__ __align__(16) ushort_t Vt[2][4096];   // [dh][key] swizzled
    __shared__ __align__(16) ushort_t Ps[8][16][64]; // per-wave swizzled P round-trip
    __shared__ float sdiag[8][16];
    __shared__ float sred[8][16];

    // 512 blocks: 16 q-blocks (128 queries) x 32 bh; big-q first, 4 heads per XCD
    int bid = blockIdx.x;
    int bh = (bid & 7) * 4 + ((bid >> 3) & 3);
    int jq = 15 - (bid >> 5);
    int q0 = jq * 128;

    int tid = threadIdx.x, wave = tid >> 6, lane = tid & 63, quad = lane >> 4, l15 = lane & 15;
    int q0w = q0 + wave * 16;
    const ushort_t* qp  = qh  + (size_t)bh * SS * DHEAD;
    const float*    kp  = kf32 + (size_t)bh * SS * DHEAD;
    const ushort_t* v1p = v1h + (size_t)bh * SS * DHEAD;
    const ushort_t* ktb = khb + (size_t)bh * 32 * 4096;
    const ushort_t* vtt = vtb + (size_t)bh * 32 * 4096;

    short8 qf[2];
    qf[0] = *reinterpret_cast<const short8*>(&qp[(q0w + l15) * DHEAD + quad * 8]);
    qf[1] = *reinterpret_cast<const short8*>(&qp[(q0w + l15) * DHEAD + 32 + quad * 8]);

    float4v Oa[4];
#pragma unroll
    for (int t = 0; t < 4; t++) Oa[t] = (float4v){0.f, 0.f, 0.f, 0.f};
    float lsum = 0.f;

    int gi = tid * 8;            // 512 threads x 16B = one full 8KB tile
    int li = (tid & 448) * 8;    // wave-uniform LDS base (1KB per wave)

    int ntiles = jq * 2 + 2;
    gload16(ktb + gi, &Ks[0][li]);
    gload16(vtt + gi, &Vt[0][li]);
    int cur = 0;

    for (int kt = 0; kt < ntiles; kt++) {
        __syncthreads();   // drains vmcnt -> buf[cur] ready; prior reads of buf[cur^1] done
        if (kt + 1 < ntiles) {
            const ushort_t* gk = ktb + (size_t)(kt + 1) * 4096;
            const ushort_t* gv = vtt + (size_t)(kt + 1) * 4096;
            int nb = cur ^ 1;
            gload16(gk + gi, &Ks[nb][li]);
            gload16(gv + gi, &Vt[nb][li]);
        }
        int kbase = kt * 64;
        if (kbase <= q0w + 15) {            // not fully masked out for this wave
            if (kbase + 63 <= q0w)          // fully unmasked for all 16 queries
                attn_tile<false>(Ks[cur], Vt[cur], kbase, quad, l15, q0w, qf,
                                 &Ps[wave][0][0], Oa, lsum);
            else
                attn_tile<true>(Ks[cur], Vt[cur], kbase, quad, l15, q0w, qf,
                                &Ps[wave][0][0], Oa, lsum);
        }
        cur ^= 1;
    }

    // reduce lsum across quads (query = q0w + l15 per lane), stash per-wave
    lsum += __shfl_xor(lsum, 16);
    lsum += __shfl_xor(lsum, 32);
    if (quad == 0) sred[wave][l15] = lsum;

    // diagonal extra key: s_d = q[i] . rope(k_roped[i]) / 8, value v1[i]
    {
        int sk = q0w + l15;
        const float* krow = kp + (size_t)sk * DHEAD;
        short8 k1lo, k1hi;
#pragma unroll
        for (int j = 0; j < 8; j++) {
            int d = quad * 8 + j;
            float f = __expf(-(float)d * LN1E4_D32);
            float th = (float)sk * f;
            float cv, sv;
            __sincosf(th, &sv, &cv);
            float a = krow[d], b2 = krow[d + 32];
            k1lo[j] = (short)f2bf(a * cv - b2 * sv);
            k1hi[j] = (short)f2bf(b2 * cv + a * sv);
        }
        float4v sd4 = (float4v){0.f, 0.f, 0.f, 0.f};
        sd4 = __builtin_amdgcn_mfma_f32_16x16x32_bf16(qf[0], k1lo, sd4, 0, 0, 0);
        sd4 = __builtin_amdgcn_mfma_f32_16x16x32_bf16(qf[1], k1hi, sd4, 0, 0, 0);
#pragma unroll
        for (int r = 0; r < 4; r++)
            if (l15 == quad * 4 + r) sdiag[wave][l15] = sd4[r] * 0.125f;
        __syncthreads();

        int b = bh >> 4, h = bh & (NHEADS - 1);
#pragma unroll
        for (int r = 0; r < 4; r++) {
            float ls = sred[wave][quad * 4 + r];
            float pd = __expf(sdiag[wave][quad * 4 + r]);
            int query = q0w + quad * 4 + r;
            float linv = 1.f / (ls + pd);
#pragma unroll
            for (int t = 0; t < 4; t++) {
                float v1v = bf2f(v1p[query * DHEAD + t * 16 + l15]);
                float o = (Oa[t][r] + pd * v1v) * linv;
                out[(b * SS + query) * DM + h * DHEAD + t * 16 + l15] = o;
            }
        }
    }
}

extern "C" void kernel_launch(void* const* d_in, const int* in_sizes, int n_in,
                              void* d_out, int out_size, void* d_ws, size_t ws_size,
                              hipStream_t stream) {
    const float* x  = (const float*)d_in[0];
    const float* y  = (const float*)d_in[1];
    const float* wq = (const float*)d_in[2];
    // d_in[3] = wk is unused by the reference
    const float* wv = (const float*)d_in[4];
    const float* wo = (const float*)d_in[5];
    float* outp  = (float*)d_out;                       // output 0: (2,2048,1024) f32
    float* k_out = outp + (size_t)BB * SS * DM;         // output 1: roped K (2,16,2048,64) f32

    char* ws = (char*)d_ws;
    ushort_t* vtb = (ushort_t*)(ws);                  // 8 MB  V^T swizzled attn tiles
    ushort_t* v1b = (ushort_t*)(ws + (8ull  << 20));  // 8 MB  V1 heads-layout bf16
    ushort_t* qhb = (ushort_t*)(ws + (16ull << 20));  // 8 MB  Q heads-layout bf16
    ushort_t* khb = (ushort_t*)(ws + (24ull << 20));  // 8 MB  roped-K swizzled attn tiles
    ushort_t* xb  = (ushort_t*)(ws + (32ull << 20));  // 8 MB  x bf16 GEMM tiles
    ushort_t* yb  = (ushort_t*)(ws + (40ull << 20));  // 8 MB  y bf16 GEMM tiles
    ushort_t* wqb = (ushort_t*)(ws + (48ull << 20));  // 2 MB
    ushort_t* wvb = (ushort_t*)(ws + (50ull << 20));  // 2 MB
    ushort_t* wob = (ushort_t*)(ws + (52ull << 20));  // 2 MB  (total 54 MB)

    cvt_tile_kernel<<<3584, 256, 0, stream>>>(x, wq, wv, wo, xb, wqb, wvb, wob);
    rope_k_kernel<<<1024, 256, 0, stream>>>(y, k_out, khb, yb);
    gemm3_kernel<<<768, 256, 0, stream>>>(xb, yb, wqb, wvb, wob, qhb, vtb, v1b);
    attn_kernel<<<512, 512, 0, stream>>>(qhb, k_out, khb, vtb, v1b, outp);
}